// Round 10
// baseline (582.431 us; speedup 1.0000x reference)
//
#include <hip/hip_runtime.h>

#define N_NODES 50000
#define N_EDGES 600000
#define D_IN 32
#define D_H 128
#define CAP 64
#define NG128 782  // groups of 64 nodes

typedef __attribute__((ext_vector_type(8))) short short8;
typedef __attribute__((ext_vector_type(4))) float f32x4;
typedef __attribute__((ext_vector_type(4))) unsigned int u32x4;

static inline int cdiv(int a, int b) { return (a + b - 1) / b; }

// bf16 round-to-nearest-even (finite inputs)
__device__ inline unsigned short f2bf(float f) {
    unsigned int b = __float_as_uint(f);
    return (unsigned short)((b + 0x7FFFu + ((b >> 16) & 1u)) >> 16);
}
__device__ inline unsigned int pack_bf16(float a, float b) {
    return (unsigned int)f2bf(a) | ((unsigned int)f2bf(b) << 16);
}
__device__ inline float bf_lo(unsigned int u) { return __uint_as_float(u << 16); }
__device__ inline float bf_hi(unsigned int u) { return __uint_as_float(u & 0xFFFF0000u); }

// ---------------- prep: zero cnt+queues + z->bf16 + weights->bf16 ----------------
// grid must cover N_NODES*D_IN/4 = 400000 threads (largest clause)

__global__ __launch_bounds__(256) void prep_kernel(
    const float* __restrict__ z, unsigned int* __restrict__ zbf,
    const float* __restrict__ Wrel0, const float* __restrict__ Wroot0,
    const float* __restrict__ Wrel, const float* __restrict__ Wroot,
    unsigned short* __restrict__ W0, unsigned short* __restrict__ W1,
    int* __restrict__ cnt, int* __restrict__ queues) {
    int i = blockIdx.x * 256 + threadIdx.x;
    if (i < 12) queues[i] = 0;
    if (i < N_NODES) cnt[i] = 0;
    if (i < N_NODES * D_IN / 4) {
        float4 v = ((const float4*)z)[i];
        ((uint2*)zbf)[i] = make_uint2(pack_bf16(v.x, v.y), pack_bf16(v.z, v.w));
    }
    if (i < 128 * 64) {
        int o = i >> 6, k = i & 63;
        float v = (k < 32) ? Wrel0[o * 32 + k] : Wroot0[o * 32 + (k - 32)];
        W0[i] = f2bf(v);
    }
    if (i < 3 * 128 * 256) {
        int L = i >> 15;
        int r = i & 32767;
        int o = r >> 8, k = r & 255;
        float v = (k < 128) ? Wrel[L * 16384 + o * 128 + k]
                            : Wroot[L * 16384 + o * 128 + (k - 128)];
        W1[i] = f2bf(v);
    }
}

// ---------------- padded edge-table build (4B packed: src16 | w_bf16<<16) ----------------

__global__ void fillpad_kernel(const int* __restrict__ src, const int* __restrict__ dst,
                               const float* __restrict__ w, int* __restrict__ cnt,
                               unsigned int* __restrict__ ep, int e) {
    int i = blockIdx.x * blockDim.x + threadIdx.x;
    if (i < e) {
        int d = dst[i];
        int slot = atomicAdd(&cnt[d], 1);
        if (slot < CAP) {
            unsigned int v = (unsigned int)src[i] | ((unsigned int)f2bf(w[i]) << 16);
            __builtin_nontemporal_store(v, ep + (size_t)d * CAP + slot);
        }
    }
}

// ---------------- agg128: XCD-chunked, work-queue + stealing ----------------
// Feature chunk c = 32 feats (64B/row, 3.2MB) -> resident in one XCD pair's L2.
// Chunk chosen from HW XCC_ID (hwreg 20); queues guarantee full coverage
// regardless of block->XCD mapping (stealing after own queue drains).
// 4 lanes per node (lane owns uint4 = 8 feats of the chunk), 64 nodes/group.

__global__ __launch_bounds__(256) void agg128_kernel(
    const unsigned int* __restrict__ xbf, const int* __restrict__ cnt,
    const unsigned int* __restrict__ ep, unsigned int* __restrict__ aggbf,
    int* __restrict__ queue, int n) {
    __shared__ int s_g;
    const int tid = threadIdx.x;
    int xcc = __builtin_amdgcn_s_getreg(63508);  // id=20 (XCC_ID), off=0, size=32
    int myc = (xcc >> 1) & 3;
    const u32x4* X4 = (const u32x4*)xbf;  // 16 u32x4 per 128-feat row
    for (int dq = 0; dq < 4; dq++) {
        int c = (myc + dq) & 3;
        for (;;) {
            __syncthreads();
            if (tid == 0) s_g = atomicAdd(&queue[c], 1);
            __syncthreads();
            int g = s_g;
            if (g >= NG128) break;
            int w = tid >> 6, l = tid & 63;
            int node = g * 64 + w * 16 + (l >> 2);
            if (node < n) {
                int s = l & 3;
                int co = c * 4 + s;
                int deg = cnt[node]; if (deg > CAP) deg = CAP;
                const unsigned int* row = ep + (size_t)node * CAP;
                float a0 = 0.f, a1 = 0.f, a2 = 0.f, a3 = 0.f,
                      a4 = 0.f, a5 = 0.f, a6 = 0.f, a7 = 0.f;
                int j = 0;
                for (; j + 4 <= deg; j += 4) {
                    unsigned int e0 = __builtin_nontemporal_load(row + j);
                    unsigned int e1 = __builtin_nontemporal_load(row + j + 1);
                    unsigned int e2 = __builtin_nontemporal_load(row + j + 2);
                    unsigned int e3 = __builtin_nontemporal_load(row + j + 3);
                    u32x4 v0 = X4[(size_t)(e0 & 0xFFFFu) * 16 + co];
                    u32x4 v1 = X4[(size_t)(e1 & 0xFFFFu) * 16 + co];
                    u32x4 v2 = X4[(size_t)(e2 & 0xFFFFu) * 16 + co];
                    u32x4 v3 = X4[(size_t)(e3 & 0xFFFFu) * 16 + co];
                    float w0 = bf_hi(e0), w1 = bf_hi(e1), w2 = bf_hi(e2), w3 = bf_hi(e3);
                    a0 += bf_lo(v0.x) * w0; a1 += bf_hi(v0.x) * w0; a2 += bf_lo(v0.y) * w0; a3 += bf_hi(v0.y) * w0;
                    a4 += bf_lo(v0.z) * w0; a5 += bf_hi(v0.z) * w0; a6 += bf_lo(v0.w) * w0; a7 += bf_hi(v0.w) * w0;
                    a0 += bf_lo(v1.x) * w1; a1 += bf_hi(v1.x) * w1; a2 += bf_lo(v1.y) * w1; a3 += bf_hi(v1.y) * w1;
                    a4 += bf_lo(v1.z) * w1; a5 += bf_hi(v1.z) * w1; a6 += bf_lo(v1.w) * w1; a7 += bf_hi(v1.w) * w1;
                    a0 += bf_lo(v2.x) * w2; a1 += bf_hi(v2.x) * w2; a2 += bf_lo(v2.y) * w2; a3 += bf_hi(v2.y) * w2;
                    a4 += bf_lo(v2.z) * w2; a5 += bf_hi(v2.z) * w2; a6 += bf_lo(v2.w) * w2; a7 += bf_hi(v2.w) * w2;
                    a0 += bf_lo(v3.x) * w3; a1 += bf_hi(v3.x) * w3; a2 += bf_lo(v3.y) * w3; a3 += bf_hi(v3.y) * w3;
                    a4 += bf_lo(v3.z) * w3; a5 += bf_hi(v3.z) * w3; a6 += bf_lo(v3.w) * w3; a7 += bf_hi(v3.w) * w3;
                }
                for (; j < deg; j++) {
                    unsigned int e0 = __builtin_nontemporal_load(row + j);
                    u32x4 v0 = X4[(size_t)(e0 & 0xFFFFu) * 16 + co];
                    float w0 = bf_hi(e0);
                    a0 += bf_lo(v0.x) * w0; a1 += bf_hi(v0.x) * w0; a2 += bf_lo(v0.y) * w0; a3 += bf_hi(v0.y) * w0;
                    a4 += bf_lo(v0.z) * w0; a5 += bf_hi(v0.z) * w0; a6 += bf_lo(v0.w) * w0; a7 += bf_hi(v0.w) * w0;
                }
                u32x4 r = (u32x4){pack_bf16(a0, a1), pack_bf16(a2, a3),
                                  pack_bf16(a4, a5), pack_bf16(a6, a7)};
                __builtin_nontemporal_store(r, (u32x4*)aggbf + (size_t)node * 16 + co);
            }
        }
    }
}

// ---------------- agg32 (zbf 3.2MB, L2-resident): 16 lanes/node, 4B edges ----------------

__global__ __launch_bounds__(256) void agg32_kernel(
    const unsigned int* __restrict__ zbf, const int* __restrict__ cnt,
    const unsigned int* __restrict__ ep, unsigned int* __restrict__ aggbf, int n) {
    int tid = threadIdx.x;
    int wid = tid >> 6, l = tid & 63;
    int sub = l >> 4, q = l & 15;
    int node = blockIdx.x * 16 + wid * 4 + sub;
    if (node >= n) return;
    int deg = cnt[node]; if (deg > CAP) deg = CAP;
    const unsigned int* row = ep + (size_t)node * CAP;
    float a0 = 0.f, a1 = 0.f;
    int j = 0;
    for (; j + 4 <= deg; j += 4) {
        unsigned int e0 = __builtin_nontemporal_load(row + j);
        unsigned int e1 = __builtin_nontemporal_load(row + j + 1);
        unsigned int e2 = __builtin_nontemporal_load(row + j + 2);
        unsigned int e3 = __builtin_nontemporal_load(row + j + 3);
        unsigned int v0 = zbf[(size_t)(e0 & 0xFFFFu) * 16 + q];
        unsigned int v1 = zbf[(size_t)(e1 & 0xFFFFu) * 16 + q];
        unsigned int v2 = zbf[(size_t)(e2 & 0xFFFFu) * 16 + q];
        unsigned int v3 = zbf[(size_t)(e3 & 0xFFFFu) * 16 + q];
        float w0 = bf_hi(e0), w1 = bf_hi(e1), w2 = bf_hi(e2), w3 = bf_hi(e3);
        a0 += bf_lo(v0) * w0; a1 += bf_hi(v0) * w0;
        a0 += bf_lo(v1) * w1; a1 += bf_hi(v1) * w1;
        a0 += bf_lo(v2) * w2; a1 += bf_hi(v2) * w2;
        a0 += bf_lo(v3) * w3; a1 += bf_hi(v3) * w3;
    }
    for (; j < deg; j++) {
        unsigned int e0 = __builtin_nontemporal_load(row + j);
        unsigned int v0 = zbf[(size_t)(e0 & 0xFFFFu) * 16 + q];
        float w0 = bf_hi(e0);
        a0 += bf_lo(v0) * w0; a1 += bf_hi(v0) * w0;
    }
    __builtin_nontemporal_store(pack_bf16(a0, a1), aggbf + (size_t)node * 16 + q);
}

// ---------------- fused linear via MFMA (bf16 in, bf16/f32 out) ----------------
// out[n][128] = relu( [agg|x][n][2K] @ W2[128][2K]^T + b ) (+skip relu)
// LDS slot d (uint2) holds A elems k=ks*32+hi16*8+jh*4.. of row mt*16+r15,
// d = ((mt*NKS+ks)*64 + hi16*16 + r15)*2 + jh. GEMM reads Afr[(mt*NKS+ks)*64+l].

template <int KH, bool SKIP, bool FINAL>
__global__ __launch_bounds__(256) void lin_kernel(
    const unsigned short* __restrict__ agg, const unsigned short* __restrict__ x,
    const unsigned short* __restrict__ W2, const float* __restrict__ bias,
    void* __restrict__ outv, int n) {
    constexpr int K2 = 2 * KH;
    constexpr int NKS = K2 / 32;
    constexpr int LOGNKS = (NKS == 2) ? 1 : 3;
    constexpr int SLOTS = 16 * K2;
    __shared__ uint2 Abuf[SLOTS];
    const int tid = threadIdx.x;
    const int n0 = blockIdx.x * 64;

#pragma unroll
    for (int it = 0; it < SLOTS / 256; it++) {
        int d = tid + it * 256;
        int jh = d & 1;
        int l = (d >> 1) & 63;
        int ks = (d >> 7) & (NKS - 1);
        int mt = d >> (7 + LOGNKS);
        int r = mt * 16 + (l & 15);
        int k = ks * 32 + ((l >> 4) << 3) + jh * 4;
        int node = n0 + r;
        uint2 v = make_uint2(0u, 0u);
        if (node < n) {
            v = (k < KH) ? *(const uint2*)(agg + (size_t)node * KH + k)
                         : *(const uint2*)(x + (size_t)node * KH + (k - KH));
        }
        Abuf[d] = v;
    }
    __syncthreads();

    const int w = tid >> 6, l = tid & 63;
    const int lo16 = l & 15, hi = l >> 4;

    f32x4 acc[4][2];
#pragma unroll
    for (int nt = 0; nt < 2; nt++) {
        float bv = bias[w * 32 + nt * 16 + lo16];
#pragma unroll
        for (int mt = 0; mt < 4; mt++) acc[mt][nt] = (f32x4){bv, bv, bv, bv};
    }

    const short8* Afr = (const short8*)Abuf;
#pragma unroll
    for (int ks = 0; ks < NKS; ks++) {
        short8 bfr[2];
#pragma unroll
        for (int nt = 0; nt < 2; nt++) {
            int o = w * 32 + nt * 16 + lo16;
            bfr[nt] = *(const short8*)(W2 + (size_t)o * K2 + ks * 32 + hi * 8);
        }
#pragma unroll
        for (int mt = 0; mt < 4; mt++) {
            short8 afr = Afr[(mt * NKS + ks) * 64 + l];
            acc[mt][0] = __builtin_amdgcn_mfma_f32_16x16x32_bf16(afr, bfr[0], acc[mt][0], 0, 0, 0);
            acc[mt][1] = __builtin_amdgcn_mfma_f32_16x16x32_bf16(afr, bfr[1], acc[mt][1], 0, 0, 0);
        }
    }

    const unsigned short* Au16 = (const unsigned short*)Abuf;
#pragma unroll
    for (int mt = 0; mt < 4; mt++) {
#pragma unroll
        for (int j = 0; j < 4; j++) {
            int node = n0 + mt * 16 + hi * 4 + j;
            if (node < n) {
#pragma unroll
                for (int nt = 0; nt < 2; nt++) {
                    int o = w * 32 + nt * 16 + lo16;
                    float v = acc[mt][nt][j];
                    v = fmaxf(v, 0.f);
                    if (SKIP) {
                        // x[node][o] from staged LDS root half (k=128+o), bf16 — same value
                        int us = (((mt * NKS + 4 + w) * 64 + (nt * 2 + (lo16 >> 3)) * 16 + hi * 4 + j) * 2
                                  + ((lo16 >> 2) & 1)) * 4 + (lo16 & 3);
                        float xr = __uint_as_float((unsigned int)Au16[us] << 16);
                        v = fmaxf(v + xr, 0.f);
                    }
                    if (FINAL)
                        ((float*)outv)[(size_t)node * D_H + o] = v;
                    else
                        ((unsigned short*)outv)[(size_t)node * D_H + o] = f2bf(v);
                }
            }
        }
    }
}

// ---------------- launch ----------------

extern "C" void kernel_launch(void* const* d_in, const int* in_sizes, int n_in,
                              void* d_out, int out_size, void* d_ws, size_t ws_size,
                              hipStream_t stream) {
    const float* z      = (const float*)d_in[0];
    const int*   eidx   = (const int*)d_in[1];
    const float* ew     = (const float*)d_in[2];
    const float* Wrel0  = (const float*)d_in[4];
    const float* brel0  = (const float*)d_in[5];
    const float* Wroot0 = (const float*)d_in[6];
    const float* Wrel   = (const float*)d_in[7];
    const float* brel   = (const float*)d_in[8];
    const float* Wroot  = (const float*)d_in[9];

    const int* src = eidx;
    const int* dst = eidx + N_EDGES;

    char* p = (char*)d_ws;
    auto alloc = [&](size_t bytes) {
        void* r = (void*)p;
        p += (bytes + 255) & ~(size_t)255;
        return r;
    };
    int*   cnt    = (int*)alloc((size_t)N_NODES * 4);
    int*   queues = (int*)alloc((size_t)12 * 4);
    unsigned int* epack = (unsigned int*)alloc((size_t)N_NODES * CAP * 4);
    unsigned int* zbf = (unsigned int*)alloc((size_t)N_NODES * D_IN * 2);
    unsigned int* agg = (unsigned int*)alloc((size_t)N_NODES * D_H * 2);
    unsigned int* h0  = (unsigned int*)alloc((size_t)N_NODES * D_H * 2);
    unsigned int* h1  = (unsigned int*)alloc((size_t)N_NODES * D_H * 2);
    unsigned short* W0bf = (unsigned short*)alloc((size_t)128 * 64 * 2);
    unsigned short* W1bf = (unsigned short*)alloc((size_t)3 * 128 * 256 * 2);
    float* outp = (float*)d_out;

    // grid MUST cover the zbf clause: N_NODES*D_IN/4 = 400000 threads
    prep_kernel<<<cdiv(N_NODES * D_IN / 4, 256), 256, 0, stream>>>(
        z, zbf, Wrel0, Wroot0, Wrel, Wroot, W0bf, W1bf, cnt, queues);

    // padded edge table (cnt -> degrees)
    fillpad_kernel<<<cdiv(N_EDGES, 256), 256, 0, stream>>>(src, dst, ew, cnt, epack, N_EDGES);

    const int agg128Grid = 2048;           // work-queue driven
    const int agg32Grid  = cdiv(N_NODES, 16);
    const int linGrid    = cdiv(N_NODES, 64);

    // L0: 32 -> 128 (no skip)
    agg32_kernel<<<agg32Grid, 256, 0, stream>>>(zbf, cnt, epack, agg, N_NODES);
    lin_kernel<32, false, false><<<linGrid, 256, 0, stream>>>(
        (const unsigned short*)agg, (const unsigned short*)zbf, W0bf, brel0, h0, N_NODES);
    // L1 (skip)
    agg128_kernel<<<agg128Grid, 256, 0, stream>>>(h0, cnt, epack, agg, queues + 0, N_NODES);
    lin_kernel<128, true, false><<<linGrid, 256, 0, stream>>>(
        (const unsigned short*)agg, (const unsigned short*)h0, W1bf, brel, h1, N_NODES);
    // L2 (skip)
    agg128_kernel<<<agg128Grid, 256, 0, stream>>>(h1, cnt, epack, agg, queues + 4, N_NODES);
    lin_kernel<128, true, false><<<linGrid, 256, 0, stream>>>(
        (const unsigned short*)agg, (const unsigned short*)h1, W1bf + 32768, brel + 128, h0, N_NODES);
    // L3 (no skip) -> d_out (f32)
    agg128_kernel<<<agg128Grid, 256, 0, stream>>>(h0, cnt, epack, agg, queues + 8, N_NODES);
    lin_kernel<128, false, true><<<linGrid, 256, 0, stream>>>(
        (const unsigned short*)agg, (const unsigned short*)h0, W1bf + 65536, brel + 256, outp, N_NODES);
}

// Round 11
// 239.431 us; speedup vs baseline: 2.4326x; 2.4326x over previous
//
#include <hip/hip_runtime.h>

#define N_NODES 50000
#define N_EDGES 600000
#define D_IN 32
#define D_H 128
#define CAP 64
#define GPC 391  // 64-node groups per half (782 total)

typedef __attribute__((ext_vector_type(8))) short short8;
typedef __attribute__((ext_vector_type(4))) float f32x4;
typedef __attribute__((ext_vector_type(4))) unsigned int u32x4;

static inline int cdiv(int a, int b) { return (a + b - 1) / b; }

// bf16 round-to-nearest-even (finite inputs)
__device__ inline unsigned short f2bf(float f) {
    unsigned int b = __float_as_uint(f);
    return (unsigned short)((b + 0x7FFFu + ((b >> 16) & 1u)) >> 16);
}
__device__ inline unsigned int pack_bf16(float a, float b) {
    return (unsigned int)f2bf(a) | ((unsigned int)f2bf(b) << 16);
}
__device__ inline float bf_lo(unsigned int u) { return __uint_as_float(u << 16); }
__device__ inline float bf_hi(unsigned int u) { return __uint_as_float(u & 0xFFFF0000u); }

// ---------------- prep: zero cnt + z->bf16 + weights->bf16 ----------------
// grid must cover N_NODES*D_IN/4 = 400000 threads (largest clause)

__global__ __launch_bounds__(256) void prep_kernel(
    const float* __restrict__ z, unsigned int* __restrict__ zbf,
    const float* __restrict__ Wrel0, const float* __restrict__ Wroot0,
    const float* __restrict__ Wrel, const float* __restrict__ Wroot,
    unsigned short* __restrict__ W0, unsigned short* __restrict__ W1,
    int* __restrict__ cnt) {
    int i = blockIdx.x * 256 + threadIdx.x;
    if (i < N_NODES) cnt[i] = 0;
    if (i < N_NODES * D_IN / 4) {
        float4 v = ((const float4*)z)[i];
        ((uint2*)zbf)[i] = make_uint2(pack_bf16(v.x, v.y), pack_bf16(v.z, v.w));
    }
    if (i < 128 * 64) {
        int o = i >> 6, k = i & 63;
        float v = (k < 32) ? Wrel0[o * 32 + k] : Wroot0[o * 32 + (k - 32)];
        W0[i] = f2bf(v);
    }
    if (i < 3 * 128 * 256) {
        int L = i >> 15;
        int r = i & 32767;
        int o = r >> 8, k = r & 255;
        float v = (k < 128) ? Wrel[L * 16384 + o * 128 + k]
                            : Wroot[L * 16384 + o * 128 + (k - 128)];
        W1[i] = f2bf(v);
    }
}

// ---------------- padded edge-table build (4B packed: src16 | w_bf16<<16) ----------------

__global__ void fillpad_kernel(const int* __restrict__ src, const int* __restrict__ dst,
                               const float* __restrict__ w, int* __restrict__ cnt,
                               unsigned int* __restrict__ ep, int e) {
    int i = blockIdx.x * blockDim.x + threadIdx.x;
    if (i < e) {
        int d = dst[i];
        int slot = atomicAdd(&cnt[d], 1);
        if (slot < CAP) {
            unsigned int v = (unsigned int)src[i] | ((unsigned int)f2bf(w[i]) << 16);
            __builtin_nontemporal_store(v, ep + (size_t)d * CAP + slot);
        }
    }
}

// ---------------- agg128: chunk-major features, static XCD grid ----------------
// Features stored chunk-major: chunk c = ushorts [(c*N + node)*32 .. +32) — a
// contiguous 3.2MB block (fits 4MB XCD L2 even at 128B line granularity).
// blockIdx&7 -> XCD (round-robin, m09); chunk = xcd>>1. Grid 8*GPC covers
// 4 chunks x 782 groups bijectively. Correctness independent of the mapping.
// 4 lanes per node (lane owns uint4 = 8 feats of the chunk), 64 nodes/block.

__global__ __launch_bounds__(256) void agg128_kernel(
    const unsigned int* __restrict__ xc, const int* __restrict__ cnt,
    const unsigned int* __restrict__ ep, unsigned int* __restrict__ aggc, int n) {
    int b = blockIdx.x;
    int xcd = b & 7, g = b >> 3;
    int c = xcd >> 1, half = xcd & 1;
    int ng = half * GPC + g;
    int tid = threadIdx.x;
    int node = ng * 64 + (tid >> 2);
    int s = tid & 3;
    if (node >= n) return;
    int deg = cnt[node]; if (deg > CAP) deg = CAP;
    const u32x4* X4 = (const u32x4*)xc;           // (cbase+src)*4 + s
    const size_t cbase = (size_t)c * N_NODES;
    const unsigned int* row = ep + (size_t)node * CAP;
    float a0 = 0.f, a1 = 0.f, a2 = 0.f, a3 = 0.f,
          a4 = 0.f, a5 = 0.f, a6 = 0.f, a7 = 0.f;
    int j = 0;
    for (; j + 4 <= deg; j += 4) {
        unsigned int e0 = __builtin_nontemporal_load(row + j);
        unsigned int e1 = __builtin_nontemporal_load(row + j + 1);
        unsigned int e2 = __builtin_nontemporal_load(row + j + 2);
        unsigned int e3 = __builtin_nontemporal_load(row + j + 3);
        u32x4 v0 = X4[(cbase + (e0 & 0xFFFFu)) * 4 + s];
        u32x4 v1 = X4[(cbase + (e1 & 0xFFFFu)) * 4 + s];
        u32x4 v2 = X4[(cbase + (e2 & 0xFFFFu)) * 4 + s];
        u32x4 v3 = X4[(cbase + (e3 & 0xFFFFu)) * 4 + s];
        float w0 = bf_hi(e0), w1 = bf_hi(e1), w2 = bf_hi(e2), w3 = bf_hi(e3);
        a0 += bf_lo(v0.x) * w0; a1 += bf_hi(v0.x) * w0; a2 += bf_lo(v0.y) * w0; a3 += bf_hi(v0.y) * w0;
        a4 += bf_lo(v0.z) * w0; a5 += bf_hi(v0.z) * w0; a6 += bf_lo(v0.w) * w0; a7 += bf_hi(v0.w) * w0;
        a0 += bf_lo(v1.x) * w1; a1 += bf_hi(v1.x) * w1; a2 += bf_lo(v1.y) * w1; a3 += bf_hi(v1.y) * w1;
        a4 += bf_lo(v1.z) * w1; a5 += bf_hi(v1.z) * w1; a6 += bf_lo(v1.w) * w1; a7 += bf_hi(v1.w) * w1;
        a0 += bf_lo(v2.x) * w2; a1 += bf_hi(v2.x) * w2; a2 += bf_lo(v2.y) * w2; a3 += bf_hi(v2.y) * w2;
        a4 += bf_lo(v2.z) * w2; a5 += bf_hi(v2.z) * w2; a6 += bf_lo(v2.w) * w2; a7 += bf_hi(v2.w) * w2;
        a0 += bf_lo(v3.x) * w3; a1 += bf_hi(v3.x) * w3; a2 += bf_lo(v3.y) * w3; a3 += bf_hi(v3.y) * w3;
        a4 += bf_lo(v3.z) * w3; a5 += bf_hi(v3.z) * w3; a6 += bf_lo(v3.w) * w3; a7 += bf_hi(v3.w) * w3;
    }
    for (; j < deg; j++) {
        unsigned int e0 = __builtin_nontemporal_load(row + j);
        u32x4 v0 = X4[(cbase + (e0 & 0xFFFFu)) * 4 + s];
        float w0 = bf_hi(e0);
        a0 += bf_lo(v0.x) * w0; a1 += bf_hi(v0.x) * w0; a2 += bf_lo(v0.y) * w0; a3 += bf_hi(v0.y) * w0;
        a4 += bf_lo(v0.z) * w0; a5 += bf_hi(v0.z) * w0; a6 += bf_lo(v0.w) * w0; a7 += bf_hi(v0.w) * w0;
    }
    u32x4 r = (u32x4){pack_bf16(a0, a1), pack_bf16(a2, a3),
                      pack_bf16(a4, a5), pack_bf16(a6, a7)};
    __builtin_nontemporal_store(r, (u32x4*)aggc + (cbase + node) * 4 + s);
}

// ---------------- agg32 (zbf 3.2MB row-major, L2-resident): 16 lanes/node ----------------

__global__ __launch_bounds__(256) void agg32_kernel(
    const unsigned int* __restrict__ zbf, const int* __restrict__ cnt,
    const unsigned int* __restrict__ ep, unsigned int* __restrict__ aggbf, int n) {
    int tid = threadIdx.x;
    int wid = tid >> 6, l = tid & 63;
    int sub = l >> 4, q = l & 15;
    int node = blockIdx.x * 16 + wid * 4 + sub;
    if (node >= n) return;
    int deg = cnt[node]; if (deg > CAP) deg = CAP;
    const unsigned int* row = ep + (size_t)node * CAP;
    float a0 = 0.f, a1 = 0.f;
    int j = 0;
    for (; j + 4 <= deg; j += 4) {
        unsigned int e0 = __builtin_nontemporal_load(row + j);
        unsigned int e1 = __builtin_nontemporal_load(row + j + 1);
        unsigned int e2 = __builtin_nontemporal_load(row + j + 2);
        unsigned int e3 = __builtin_nontemporal_load(row + j + 3);
        unsigned int v0 = zbf[(size_t)(e0 & 0xFFFFu) * 16 + q];
        unsigned int v1 = zbf[(size_t)(e1 & 0xFFFFu) * 16 + q];
        unsigned int v2 = zbf[(size_t)(e2 & 0xFFFFu) * 16 + q];
        unsigned int v3 = zbf[(size_t)(e3 & 0xFFFFu) * 16 + q];
        float w0 = bf_hi(e0), w1 = bf_hi(e1), w2 = bf_hi(e2), w3 = bf_hi(e3);
        a0 += bf_lo(v0) * w0; a1 += bf_hi(v0) * w0;
        a0 += bf_lo(v1) * w1; a1 += bf_hi(v1) * w1;
        a0 += bf_lo(v2) * w2; a1 += bf_hi(v2) * w2;
        a0 += bf_lo(v3) * w3; a1 += bf_hi(v3) * w3;
    }
    for (; j < deg; j++) {
        unsigned int e0 = __builtin_nontemporal_load(row + j);
        unsigned int v0 = zbf[(size_t)(e0 & 0xFFFFu) * 16 + q];
        float w0 = bf_hi(e0);
        a0 += bf_lo(v0) * w0; a1 += bf_hi(v0) * w0;
    }
    aggbf[(size_t)node * 16 + q] = pack_bf16(a0, a1);
}

// ---------------- fused linear via MFMA ----------------
// out = relu([agg|x] @ W2^T + b) (+skip relu). KH==128: agg/x are CHUNK-MAJOR
// (element [node][k] at ((k>>5)*N + node)*32 + (k&31) ushorts); KH==32 row-major.
// Non-FINAL output h is chunk-major; FINAL writes f32 row-major to d_out.
// LDS layout as before: slot d holds k=ks*32+hi16*8+jh*4.. of row mt*16+r15.

template <int KH, bool SKIP, bool FINAL>
__global__ __launch_bounds__(256) void lin_kernel(
    const unsigned short* __restrict__ agg, const unsigned short* __restrict__ x,
    const unsigned short* __restrict__ W2, const float* __restrict__ bias,
    void* __restrict__ outv, int n) {
    constexpr int K2 = 2 * KH;
    constexpr int NKS = K2 / 32;
    constexpr int LOGNKS = (NKS == 2) ? 1 : 3;
    constexpr int SLOTS = 16 * K2;
    __shared__ uint2 Abuf[SLOTS];
    const int tid = threadIdx.x;
    const int n0 = blockIdx.x * 64;

#pragma unroll
    for (int it = 0; it < SLOTS / 256; it++) {
        int d = tid + it * 256;
        int jh = d & 1;
        int l = (d >> 1) & 63;
        int ks = (d >> 7) & (NKS - 1);
        int mt = d >> (7 + LOGNKS);
        int r = mt * 16 + (l & 15);
        int k = ks * 32 + ((l >> 4) << 3) + jh * 4;
        int node = n0 + r;
        uint2 v = make_uint2(0u, 0u);
        if (node < n) {
            int kk = (k < KH) ? k : (k - KH);
            const unsigned short* base = (k < KH) ? agg : x;
            size_t addr;
            if (KH == 128)
                addr = ((size_t)(kk >> 5) * N_NODES + node) * 32 + (kk & 31);
            else
                addr = (size_t)node * KH + kk;
            v = *(const uint2*)(base + addr);
        }
        Abuf[d] = v;
    }
    __syncthreads();

    const int w = tid >> 6, l = tid & 63;
    const int lo16 = l & 15, hi = l >> 4;

    f32x4 acc[4][2];
#pragma unroll
    for (int nt = 0; nt < 2; nt++) {
        float bv = bias[w * 32 + nt * 16 + lo16];
#pragma unroll
        for (int mt = 0; mt < 4; mt++) acc[mt][nt] = (f32x4){bv, bv, bv, bv};
    }

    const short8* Afr = (const short8*)Abuf;
#pragma unroll
    for (int ks = 0; ks < NKS; ks++) {
        short8 bfr[2];
#pragma unroll
        for (int nt = 0; nt < 2; nt++) {
            int o = w * 32 + nt * 16 + lo16;
            bfr[nt] = *(const short8*)(W2 + (size_t)o * K2 + ks * 32 + hi * 8);
        }
#pragma unroll
        for (int mt = 0; mt < 4; mt++) {
            short8 afr = Afr[(mt * NKS + ks) * 64 + l];
            acc[mt][0] = __builtin_amdgcn_mfma_f32_16x16x32_bf16(afr, bfr[0], acc[mt][0], 0, 0, 0);
            acc[mt][1] = __builtin_amdgcn_mfma_f32_16x16x32_bf16(afr, bfr[1], acc[mt][1], 0, 0, 0);
        }
    }

    const unsigned short* Au16 = (const unsigned short*)Abuf;
#pragma unroll
    for (int mt = 0; mt < 4; mt++) {
#pragma unroll
        for (int j = 0; j < 4; j++) {
            int node = n0 + mt * 16 + hi * 4 + j;
            if (node < n) {
#pragma unroll
                for (int nt = 0; nt < 2; nt++) {
                    int o = w * 32 + nt * 16 + lo16;
                    float v = acc[mt][nt][j];
                    v = fmaxf(v, 0.f);
                    if (SKIP) {
                        // x[node][o] from staged LDS root half (k=128+o), bf16 — same value
                        int us = (((mt * NKS + 4 + w) * 64 + (nt * 2 + (lo16 >> 3)) * 16 + hi * 4 + j) * 2
                                  + ((lo16 >> 2) & 1)) * 4 + (lo16 & 3);
                        float xr = __uint_as_float((unsigned int)Au16[us] << 16);
                        v = fmaxf(v + xr, 0.f);
                    }
                    if (FINAL) {
                        ((float*)outv)[(size_t)node * D_H + o] = v;
                    } else {
                        // chunk-major h: chunk = o>>5 = w
                        ((unsigned short*)outv)[((size_t)w * N_NODES + node) * 32 + nt * 16 + lo16] = f2bf(v);
                    }
                }
            }
        }
    }
}

// ---------------- launch ----------------

extern "C" void kernel_launch(void* const* d_in, const int* in_sizes, int n_in,
                              void* d_out, int out_size, void* d_ws, size_t ws_size,
                              hipStream_t stream) {
    const float* z      = (const float*)d_in[0];
    const int*   eidx   = (const int*)d_in[1];
    const float* ew     = (const float*)d_in[2];
    const float* Wrel0  = (const float*)d_in[4];
    const float* brel0  = (const float*)d_in[5];
    const float* Wroot0 = (const float*)d_in[6];
    const float* Wrel   = (const float*)d_in[7];
    const float* brel   = (const float*)d_in[8];
    const float* Wroot  = (const float*)d_in[9];

    const int* src = eidx;
    const int* dst = eidx + N_EDGES;

    char* p = (char*)d_ws;
    auto alloc = [&](size_t bytes) {
        void* r = (void*)p;
        p += (bytes + 255) & ~(size_t)255;
        return r;
    };
    int*   cnt    = (int*)alloc((size_t)N_NODES * 4);
    unsigned int* epack = (unsigned int*)alloc((size_t)N_NODES * CAP * 4);
    unsigned int* zbf = (unsigned int*)alloc((size_t)N_NODES * D_IN * 2);
    unsigned int* agg = (unsigned int*)alloc((size_t)N_NODES * D_H * 2);
    unsigned int* h0  = (unsigned int*)alloc((size_t)N_NODES * D_H * 2);
    unsigned int* h1  = (unsigned int*)alloc((size_t)N_NODES * D_H * 2);
    unsigned short* W0bf = (unsigned short*)alloc((size_t)128 * 64 * 2);
    unsigned short* W1bf = (unsigned short*)alloc((size_t)3 * 128 * 256 * 2);
    float* outp = (float*)d_out;

    // grid MUST cover the zbf clause: N_NODES*D_IN/4 = 400000 threads
    prep_kernel<<<cdiv(N_NODES * D_IN / 4, 256), 256, 0, stream>>>(
        z, zbf, Wrel0, Wroot0, Wrel, Wroot, W0bf, W1bf, cnt);

    // padded edge table (cnt -> degrees)
    fillpad_kernel<<<cdiv(N_EDGES, 256), 256, 0, stream>>>(src, dst, ew, cnt, epack, N_EDGES);

    const int agg128Grid = 8 * GPC;  // 3128: 4 chunks x 782 groups, XCD-mapped
    const int agg32Grid  = cdiv(N_NODES, 16);
    const int linGrid    = cdiv(N_NODES, 64);

    // L0: 32 -> 128 (no skip); h0 written chunk-major
    agg32_kernel<<<agg32Grid, 256, 0, stream>>>(zbf, cnt, epack, agg, N_NODES);
    lin_kernel<32, false, false><<<linGrid, 256, 0, stream>>>(
        (const unsigned short*)agg, (const unsigned short*)zbf, W0bf, brel0, h0, N_NODES);
    // L1 (skip)
    agg128_kernel<<<agg128Grid, 256, 0, stream>>>(h0, cnt, epack, agg, N_NODES);
    lin_kernel<128, true, false><<<linGrid, 256, 0, stream>>>(
        (const unsigned short*)agg, (const unsigned short*)h0, W1bf, brel, h1, N_NODES);
    // L2 (skip)
    agg128_kernel<<<agg128Grid, 256, 0, stream>>>(h1, cnt, epack, agg, N_NODES);
    lin_kernel<128, true, false><<<linGrid, 256, 0, stream>>>(
        (const unsigned short*)agg, (const unsigned short*)h1, W1bf + 32768, brel + 128, h0, N_NODES);
    // L3 (no skip) -> d_out (f32 row-major)
    agg128_kernel<<<agg128Grid, 256, 0, stream>>>(h0, cnt, epack, agg, N_NODES);
    lin_kernel<128, false, true><<<linGrid, 256, 0, stream>>>(
        (const unsigned short*)agg, (const unsigned short*)h0, W1bf + 65536, brel + 256, outp, N_NODES);
}

// Round 12
// 209.903 us; speedup vs baseline: 2.7748x; 1.1407x over previous
//
#include <hip/hip_runtime.h>

#define N_NODES 50000
#define N_EDGES 600000
#define D_IN 32
#define D_H 128
#define CAP 64

typedef __attribute__((ext_vector_type(8))) short short8;
typedef __attribute__((ext_vector_type(4))) float f32x4;
typedef __attribute__((ext_vector_type(4))) unsigned int u32x4;

static inline int cdiv(int a, int b) { return (a + b - 1) / b; }

// bf16 round-to-nearest-even (finite inputs)
__device__ inline unsigned short f2bf(float f) {
    unsigned int b = __float_as_uint(f);
    return (unsigned short)((b + 0x7FFFu + ((b >> 16) & 1u)) >> 16);
}
__device__ inline unsigned int pack_bf16(float a, float b) {
    return (unsigned int)f2bf(a) | ((unsigned int)f2bf(b) << 16);
}
__device__ inline float bf_lo(unsigned int u) { return __uint_as_float(u << 16); }
__device__ inline float bf_hi(unsigned int u) { return __uint_as_float(u & 0xFFFF0000u); }

// ---------------- prep: zero cnt + z->bf16 + weights->bf16 ----------------
// grid must cover N_NODES*D_IN/4 = 400000 threads (largest clause)

__global__ __launch_bounds__(256) void prep_kernel(
    const float* __restrict__ z, unsigned int* __restrict__ zbf,
    const float* __restrict__ Wrel0, const float* __restrict__ Wroot0,
    const float* __restrict__ Wrel, const float* __restrict__ Wroot,
    unsigned short* __restrict__ W0, unsigned short* __restrict__ W1,
    int* __restrict__ cnt) {
    int i = blockIdx.x * 256 + threadIdx.x;
    if (i < N_NODES) cnt[i] = 0;
    if (i < N_NODES * D_IN / 4) {
        float4 v = ((const float4*)z)[i];
        ((uint2*)zbf)[i] = make_uint2(pack_bf16(v.x, v.y), pack_bf16(v.z, v.w));
    }
    if (i < 128 * 64) {
        int o = i >> 6, k = i & 63;
        float v = (k < 32) ? Wrel0[o * 32 + k] : Wroot0[o * 32 + (k - 32)];
        W0[i] = f2bf(v);
    }
    if (i < 3 * 128 * 256) {
        int L = i >> 15;
        int r = i & 32767;
        int o = r >> 8, k = r & 255;
        float v = (k < 128) ? Wrel[L * 16384 + o * 128 + k]
                            : Wroot[L * 16384 + o * 128 + (k - 128)];
        W1[i] = f2bf(v);
    }
}

// ---------------- padded edge-table build (4B packed: src16 | w_bf16<<16) ----------------
// ep[d*CAP + slot]; cnt[d] ends as the degree. P(deg>CAP)~1e-30 for Poisson(12).

__global__ void fillpad_kernel(const int* __restrict__ src, const int* __restrict__ dst,
                               const float* __restrict__ w, int* __restrict__ cnt,
                               unsigned int* __restrict__ ep, int e) {
    int i = blockIdx.x * blockDim.x + threadIdx.x;
    if (i < e) {
        int d = dst[i];
        int slot = atomicAdd(&cnt[d], 1);
        if (slot < CAP) {
            unsigned int v = (unsigned int)src[i] | ((unsigned int)f2bf(w[i]) << 16);
            __builtin_nontemporal_store(v, ep + (size_t)d * CAP + slot);
        }
    }
}

// ---------------- aggregation (pull, padded table, bf16 features, row-major) ----------------

// 128-dim: 16 lanes per node, lane owns u32x4 (8 features, 16B); unroll-4
__global__ __launch_bounds__(256) void agg128_kernel(
    const unsigned int* __restrict__ xbf, const int* __restrict__ cnt,
    const unsigned int* __restrict__ ep, unsigned int* __restrict__ aggbf, int n) {
    int tid = threadIdx.x;
    int wid = tid >> 6, l = tid & 63;
    int sub = l >> 4, q = l & 15;
    int node = blockIdx.x * 16 + wid * 4 + sub;
    if (node >= n) return;
    int deg = cnt[node]; if (deg > CAP) deg = CAP;
    const u32x4* X4 = (const u32x4*)xbf;  // 16 u32x4 per 128-feat row
    const unsigned int* row = ep + (size_t)node * CAP;
    float a0 = 0.f, a1 = 0.f, a2 = 0.f, a3 = 0.f,
          a4 = 0.f, a5 = 0.f, a6 = 0.f, a7 = 0.f;
    int j = 0;
    for (; j + 4 <= deg; j += 4) {
        unsigned int e0 = __builtin_nontemporal_load(row + j);
        unsigned int e1 = __builtin_nontemporal_load(row + j + 1);
        unsigned int e2 = __builtin_nontemporal_load(row + j + 2);
        unsigned int e3 = __builtin_nontemporal_load(row + j + 3);
        u32x4 v0 = X4[(size_t)(e0 & 0xFFFFu) * 16 + q];
        u32x4 v1 = X4[(size_t)(e1 & 0xFFFFu) * 16 + q];
        u32x4 v2 = X4[(size_t)(e2 & 0xFFFFu) * 16 + q];
        u32x4 v3 = X4[(size_t)(e3 & 0xFFFFu) * 16 + q];
        float w0 = bf_hi(e0), w1 = bf_hi(e1), w2 = bf_hi(e2), w3 = bf_hi(e3);
        a0 += bf_lo(v0.x) * w0; a1 += bf_hi(v0.x) * w0; a2 += bf_lo(v0.y) * w0; a3 += bf_hi(v0.y) * w0;
        a4 += bf_lo(v0.z) * w0; a5 += bf_hi(v0.z) * w0; a6 += bf_lo(v0.w) * w0; a7 += bf_hi(v0.w) * w0;
        a0 += bf_lo(v1.x) * w1; a1 += bf_hi(v1.x) * w1; a2 += bf_lo(v1.y) * w1; a3 += bf_hi(v1.y) * w1;
        a4 += bf_lo(v1.z) * w1; a5 += bf_hi(v1.z) * w1; a6 += bf_lo(v1.w) * w1; a7 += bf_hi(v1.w) * w1;
        a0 += bf_lo(v2.x) * w2; a1 += bf_hi(v2.x) * w2; a2 += bf_lo(v2.y) * w2; a3 += bf_hi(v2.y) * w2;
        a4 += bf_lo(v2.z) * w2; a5 += bf_hi(v2.z) * w2; a6 += bf_lo(v2.w) * w2; a7 += bf_hi(v2.w) * w2;
        a0 += bf_lo(v3.x) * w3; a1 += bf_hi(v3.x) * w3; a2 += bf_lo(v3.y) * w3; a3 += bf_hi(v3.y) * w3;
        a4 += bf_lo(v3.z) * w3; a5 += bf_hi(v3.z) * w3; a6 += bf_lo(v3.w) * w3; a7 += bf_hi(v3.w) * w3;
    }
    for (; j < deg; j++) {
        unsigned int e0 = __builtin_nontemporal_load(row + j);
        u32x4 v0 = X4[(size_t)(e0 & 0xFFFFu) * 16 + q];
        float w0 = bf_hi(e0);
        a0 += bf_lo(v0.x) * w0; a1 += bf_hi(v0.x) * w0; a2 += bf_lo(v0.y) * w0; a3 += bf_hi(v0.y) * w0;
        a4 += bf_lo(v0.z) * w0; a5 += bf_hi(v0.z) * w0; a6 += bf_lo(v0.w) * w0; a7 += bf_hi(v0.w) * w0;
    }
    u32x4 r = (u32x4){pack_bf16(a0, a1), pack_bf16(a2, a3),
                      pack_bf16(a4, a5), pack_bf16(a6, a7)};
    __builtin_nontemporal_store(r, (u32x4*)aggbf + (size_t)node * 16 + q);
}

// 32-dim bf16 z: 16 lanes per node, lane owns uint (2 features); unroll-4
__global__ __launch_bounds__(256) void agg32_kernel(
    const unsigned int* __restrict__ zbf, const int* __restrict__ cnt,
    const unsigned int* __restrict__ ep, unsigned int* __restrict__ aggbf, int n) {
    int tid = threadIdx.x;
    int wid = tid >> 6, l = tid & 63;
    int sub = l >> 4, q = l & 15;
    int node = blockIdx.x * 16 + wid * 4 + sub;
    if (node >= n) return;
    int deg = cnt[node]; if (deg > CAP) deg = CAP;
    const unsigned int* row = ep + (size_t)node * CAP;
    float a0 = 0.f, a1 = 0.f;
    int j = 0;
    for (; j + 4 <= deg; j += 4) {
        unsigned int e0 = __builtin_nontemporal_load(row + j);
        unsigned int e1 = __builtin_nontemporal_load(row + j + 1);
        unsigned int e2 = __builtin_nontemporal_load(row + j + 2);
        unsigned int e3 = __builtin_nontemporal_load(row + j + 3);
        unsigned int v0 = zbf[(size_t)(e0 & 0xFFFFu) * 16 + q];
        unsigned int v1 = zbf[(size_t)(e1 & 0xFFFFu) * 16 + q];
        unsigned int v2 = zbf[(size_t)(e2 & 0xFFFFu) * 16 + q];
        unsigned int v3 = zbf[(size_t)(e3 & 0xFFFFu) * 16 + q];
        float w0 = bf_hi(e0), w1 = bf_hi(e1), w2 = bf_hi(e2), w3 = bf_hi(e3);
        a0 += bf_lo(v0) * w0; a1 += bf_hi(v0) * w0;
        a0 += bf_lo(v1) * w1; a1 += bf_hi(v1) * w1;
        a0 += bf_lo(v2) * w2; a1 += bf_hi(v2) * w2;
        a0 += bf_lo(v3) * w3; a1 += bf_hi(v3) * w3;
    }
    for (; j < deg; j++) {
        unsigned int e0 = __builtin_nontemporal_load(row + j);
        unsigned int v0 = zbf[(size_t)(e0 & 0xFFFFu) * 16 + q];
        float w0 = bf_hi(e0);
        a0 += bf_lo(v0) * w0; a1 += bf_hi(v0) * w0;
    }
    __builtin_nontemporal_store(pack_bf16(a0, a1), aggbf + (size_t)node * 16 + q);
}

// ---------------- fused linear via MFMA (bf16 in, bf16/f32 out, row-major) ----------------
// out[n][128] = relu( [agg|x][n][2K] @ W2[128][2K]^T + b ) (+skip relu)
// LDS slot d (uint2) holds A elems k=ks*32+hi16*8+jh*4.. of row mt*16+r15,
// d = ((mt*NKS+ks)*64 + hi16*16 + r15)*2 + jh. GEMM reads Afr[(mt*NKS+ks)*64+l].

template <int KH, bool SKIP, bool FINAL>
__global__ __launch_bounds__(256) void lin_kernel(
    const unsigned short* __restrict__ agg, const unsigned short* __restrict__ x,
    const unsigned short* __restrict__ W2, const float* __restrict__ bias,
    void* __restrict__ outv, int n) {
    constexpr int K2 = 2 * KH;
    constexpr int NKS = K2 / 32;
    constexpr int LOGNKS = (NKS == 2) ? 1 : 3;
    constexpr int SLOTS = 16 * K2;
    __shared__ uint2 Abuf[SLOTS];
    const int tid = threadIdx.x;
    const int n0 = blockIdx.x * 64;

#pragma unroll
    for (int it = 0; it < SLOTS / 256; it++) {
        int d = tid + it * 256;
        int jh = d & 1;
        int l = (d >> 1) & 63;
        int ks = (d >> 7) & (NKS - 1);
        int mt = d >> (7 + LOGNKS);
        int r = mt * 16 + (l & 15);
        int k = ks * 32 + ((l >> 4) << 3) + jh * 4;
        int node = n0 + r;
        uint2 v = make_uint2(0u, 0u);
        if (node < n) {
            v = (k < KH) ? *(const uint2*)(agg + (size_t)node * KH + k)
                         : *(const uint2*)(x + (size_t)node * KH + (k - KH));
        }
        Abuf[d] = v;
    }
    __syncthreads();

    const int w = tid >> 6, l = tid & 63;
    const int lo16 = l & 15, hi = l >> 4;

    f32x4 acc[4][2];
#pragma unroll
    for (int nt = 0; nt < 2; nt++) {
        float bv = bias[w * 32 + nt * 16 + lo16];
#pragma unroll
        for (int mt = 0; mt < 4; mt++) acc[mt][nt] = (f32x4){bv, bv, bv, bv};
    }

    const short8* Afr = (const short8*)Abuf;
#pragma unroll
    for (int ks = 0; ks < NKS; ks++) {
        short8 bfr[2];
#pragma unroll
        for (int nt = 0; nt < 2; nt++) {
            int o = w * 32 + nt * 16 + lo16;
            bfr[nt] = *(const short8*)(W2 + (size_t)o * K2 + ks * 32 + hi * 8);
        }
#pragma unroll
        for (int mt = 0; mt < 4; mt++) {
            short8 afr = Afr[(mt * NKS + ks) * 64 + l];
            acc[mt][0] = __builtin_amdgcn_mfma_f32_16x16x32_bf16(afr, bfr[0], acc[mt][0], 0, 0, 0);
            acc[mt][1] = __builtin_amdgcn_mfma_f32_16x16x32_bf16(afr, bfr[1], acc[mt][1], 0, 0, 0);
        }
    }

    const unsigned short* Au16 = (const unsigned short*)Abuf;
#pragma unroll
    for (int mt = 0; mt < 4; mt++) {
#pragma unroll
        for (int j = 0; j < 4; j++) {
            int node = n0 + mt * 16 + hi * 4 + j;
            if (node < n) {
#pragma unroll
                for (int nt = 0; nt < 2; nt++) {
                    int o = w * 32 + nt * 16 + lo16;
                    float v = acc[mt][nt][j];
                    v = fmaxf(v, 0.f);
                    if (SKIP) {
                        // x[node][o] from staged LDS root half (k=128+o), bf16 — same value
                        int us = (((mt * NKS + 4 + w) * 64 + (nt * 2 + (lo16 >> 3)) * 16 + hi * 4 + j) * 2
                                  + ((lo16 >> 2) & 1)) * 4 + (lo16 & 3);
                        float xr = __uint_as_float((unsigned int)Au16[us] << 16);
                        v = fmaxf(v + xr, 0.f);
                    }
                    if (FINAL)
                        ((float*)outv)[(size_t)node * D_H + o] = v;
                    else
                        ((unsigned short*)outv)[(size_t)node * D_H + o] = f2bf(v);
                }
            }
        }
    }
}

// ---------------- launch ----------------

extern "C" void kernel_launch(void* const* d_in, const int* in_sizes, int n_in,
                              void* d_out, int out_size, void* d_ws, size_t ws_size,
                              hipStream_t stream) {
    const float* z      = (const float*)d_in[0];
    const int*   eidx   = (const int*)d_in[1];
    const float* ew     = (const float*)d_in[2];
    const float* Wrel0  = (const float*)d_in[4];
    const float* brel0  = (const float*)d_in[5];
    const float* Wroot0 = (const float*)d_in[6];
    const float* Wrel   = (const float*)d_in[7];
    const float* brel   = (const float*)d_in[8];
    const float* Wroot  = (const float*)d_in[9];

    const int* src = eidx;
    const int* dst = eidx + N_EDGES;

    char* p = (char*)d_ws;
    auto alloc = [&](size_t bytes) {
        void* r = (void*)p;
        p += (bytes + 255) & ~(size_t)255;
        return r;
    };
    int*   cnt    = (int*)alloc((size_t)N_NODES * 4);
    unsigned int* epack = (unsigned int*)alloc((size_t)N_NODES * CAP * 4);
    unsigned int* zbf = (unsigned int*)alloc((size_t)N_NODES * D_IN * 2);
    unsigned int* agg = (unsigned int*)alloc((size_t)N_NODES * D_H * 2);
    unsigned int* h0  = (unsigned int*)alloc((size_t)N_NODES * D_H * 2);
    unsigned int* h1  = (unsigned int*)alloc((size_t)N_NODES * D_H * 2);
    unsigned short* W0bf = (unsigned short*)alloc((size_t)128 * 64 * 2);
    unsigned short* W1bf = (unsigned short*)alloc((size_t)3 * 128 * 256 * 2);
    float* outp = (float*)d_out;

    // grid MUST cover the zbf clause: N_NODES*D_IN/4 = 400000 threads
    prep_kernel<<<cdiv(N_NODES * D_IN / 4, 256), 256, 0, stream>>>(
        z, zbf, Wrel0, Wroot0, Wrel, Wroot, W0bf, W1bf, cnt);

    // padded edge table (cnt -> degrees)
    fillpad_kernel<<<cdiv(N_EDGES, 256), 256, 0, stream>>>(src, dst, ew, cnt, epack, N_EDGES);

    const int aggGrid = cdiv(N_NODES, 16);
    const int linGrid = cdiv(N_NODES, 64);

    // L0: 32 -> 128 (no skip)
    agg32_kernel<<<aggGrid, 256, 0, stream>>>(zbf, cnt, epack, agg, N_NODES);
    lin_kernel<32, false, false><<<linGrid, 256, 0, stream>>>(
        (const unsigned short*)agg, (const unsigned short*)zbf, W0bf, brel0, h0, N_NODES);
    // L1 (skip)
    agg128_kernel<<<aggGrid, 256, 0, stream>>>(h0, cnt, epack, agg, N_NODES);
    lin_kernel<128, true, false><<<linGrid, 256, 0, stream>>>(
        (const unsigned short*)agg, (const unsigned short*)h0, W1bf, brel, h1, N_NODES);
    // L2 (skip)
    agg128_kernel<<<aggGrid, 256, 0, stream>>>(h1, cnt, epack, agg, N_NODES);
    lin_kernel<128, true, false><<<linGrid, 256, 0, stream>>>(
        (const unsigned short*)agg, (const unsigned short*)h1, W1bf + 32768, brel + 128, h0, N_NODES);
    // L3 (no skip) -> d_out (f32)
    agg128_kernel<<<aggGrid, 256, 0, stream>>>(h0, cnt, epack, agg, N_NODES);
    lin_kernel<128, false, true><<<linGrid, 256, 0, stream>>>(
        (const unsigned short*)agg, (const unsigned short*)h0, W1bf + 65536, brel + 256, outp, N_NODES);
}

// Round 13
// 197.990 us; speedup vs baseline: 2.9417x; 1.0602x over previous
//
#include <hip/hip_runtime.h>

#define N_NODES 50000
#define N_EDGES 600000
#define D_IN 32
#define D_H 128
#define CAP 64

typedef __attribute__((ext_vector_type(8))) short short8;
typedef __attribute__((ext_vector_type(4))) float f32x4;
typedef __attribute__((ext_vector_type(4))) unsigned int u32x4;

static inline int cdiv(int a, int b) { return (a + b - 1) / b; }

// bf16 round-to-nearest-even (finite inputs)
__device__ inline unsigned short f2bf(float f) {
    unsigned int b = __float_as_uint(f);
    return (unsigned short)((b + 0x7FFFu + ((b >> 16) & 1u)) >> 16);
}
__device__ inline unsigned int pack_bf16(float a, float b) {
    return (unsigned int)f2bf(a) | ((unsigned int)f2bf(b) << 16);
}
__device__ inline float bf_lo(unsigned int u) { return __uint_as_float(u << 16); }
__device__ inline float bf_hi(unsigned int u) { return __uint_as_float(u & 0xFFFF0000u); }

// ---------------- prep: zero cnt + z->bf16 + weights->bf16 ----------------
// grid must cover N_NODES*D_IN/4 = 400000 threads (largest clause)

__global__ __launch_bounds__(256) void prep_kernel(
    const float* __restrict__ z, unsigned int* __restrict__ zbf,
    const float* __restrict__ Wrel0, const float* __restrict__ Wroot0,
    const float* __restrict__ Wrel, const float* __restrict__ Wroot,
    unsigned short* __restrict__ W0, unsigned short* __restrict__ W1,
    int* __restrict__ cnt) {
    int i = blockIdx.x * 256 + threadIdx.x;
    if (i < N_NODES) cnt[i] = 0;
    if (i < N_NODES * D_IN / 4) {
        float4 v = ((const float4*)z)[i];
        ((uint2*)zbf)[i] = make_uint2(pack_bf16(v.x, v.y), pack_bf16(v.z, v.w));
    }
    if (i < 128 * 64) {
        int o = i >> 6, k = i & 63;
        float v = (k < 32) ? Wrel0[o * 32 + k] : Wroot0[o * 32 + (k - 32)];
        W0[i] = f2bf(v);
    }
    if (i < 3 * 128 * 256) {
        int L = i >> 15;
        int r = i & 32767;
        int o = r >> 8, k = r & 255;
        float v = (k < 128) ? Wrel[L * 16384 + o * 128 + k]
                            : Wroot[L * 16384 + o * 128 + (k - 128)];
        W1[i] = f2bf(v);
    }
}

// ---------------- padded edge-table build (4B packed: src16 | w_bf16<<16) ----------------
// ep[d*CAP + slot]; cnt[d] ends as the degree. P(deg>CAP)~1e-30 for Poisson(12).

__global__ void fillpad_kernel(const int* __restrict__ src, const int* __restrict__ dst,
                               const float* __restrict__ w, int* __restrict__ cnt,
                               unsigned int* __restrict__ ep, int e) {
    int i = blockIdx.x * blockDim.x + threadIdx.x;
    if (i < e) {
        int d = dst[i];
        int slot = atomicAdd(&cnt[d], 1);
        if (slot < CAP) ep[(size_t)d * CAP + slot] = (unsigned int)src[i] | ((unsigned int)f2bf(w[i]) << 16);
    }
}

// ---------------- aggregation (pull, padded table, bf16 features, row-major) ----------------

// 128-dim: 16 lanes per node, lane owns u32x4 (8 features, 16B); unroll-4
__global__ __launch_bounds__(256) void agg128_kernel(
    const unsigned int* __restrict__ xbf, const int* __restrict__ cnt,
    const unsigned int* __restrict__ ep, unsigned int* __restrict__ aggbf, int n) {
    int tid = threadIdx.x;
    int wid = tid >> 6, l = tid & 63;
    int sub = l >> 4, q = l & 15;
    int node = blockIdx.x * 16 + wid * 4 + sub;
    if (node >= n) return;
    int deg = cnt[node]; if (deg > CAP) deg = CAP;
    const u32x4* X4 = (const u32x4*)xbf;  // 16 u32x4 per 128-feat row
    const unsigned int* row = ep + (size_t)node * CAP;
    float a0 = 0.f, a1 = 0.f, a2 = 0.f, a3 = 0.f,
          a4 = 0.f, a5 = 0.f, a6 = 0.f, a7 = 0.f;
    int j = 0;
    for (; j + 4 <= deg; j += 4) {
        unsigned int e0 = __builtin_nontemporal_load(row + j);
        unsigned int e1 = __builtin_nontemporal_load(row + j + 1);
        unsigned int e2 = __builtin_nontemporal_load(row + j + 2);
        unsigned int e3 = __builtin_nontemporal_load(row + j + 3);
        u32x4 v0 = X4[(size_t)(e0 & 0xFFFFu) * 16 + q];
        u32x4 v1 = X4[(size_t)(e1 & 0xFFFFu) * 16 + q];
        u32x4 v2 = X4[(size_t)(e2 & 0xFFFFu) * 16 + q];
        u32x4 v3 = X4[(size_t)(e3 & 0xFFFFu) * 16 + q];
        float w0 = bf_hi(e0), w1 = bf_hi(e1), w2 = bf_hi(e2), w3 = bf_hi(e3);
        a0 += bf_lo(v0.x) * w0; a1 += bf_hi(v0.x) * w0; a2 += bf_lo(v0.y) * w0; a3 += bf_hi(v0.y) * w0;
        a4 += bf_lo(v0.z) * w0; a5 += bf_hi(v0.z) * w0; a6 += bf_lo(v0.w) * w0; a7 += bf_hi(v0.w) * w0;
        a0 += bf_lo(v1.x) * w1; a1 += bf_hi(v1.x) * w1; a2 += bf_lo(v1.y) * w1; a3 += bf_hi(v1.y) * w1;
        a4 += bf_lo(v1.z) * w1; a5 += bf_hi(v1.z) * w1; a6 += bf_lo(v1.w) * w1; a7 += bf_hi(v1.w) * w1;
        a0 += bf_lo(v2.x) * w2; a1 += bf_hi(v2.x) * w2; a2 += bf_lo(v2.y) * w2; a3 += bf_hi(v2.y) * w2;
        a4 += bf_lo(v2.z) * w2; a5 += bf_hi(v2.z) * w2; a6 += bf_lo(v2.w) * w2; a7 += bf_hi(v2.w) * w2;
        a0 += bf_lo(v3.x) * w3; a1 += bf_hi(v3.x) * w3; a2 += bf_lo(v3.y) * w3; a3 += bf_hi(v3.y) * w3;
        a4 += bf_lo(v3.z) * w3; a5 += bf_hi(v3.z) * w3; a6 += bf_lo(v3.w) * w3; a7 += bf_hi(v3.w) * w3;
    }
    for (; j < deg; j++) {
        unsigned int e0 = __builtin_nontemporal_load(row + j);
        u32x4 v0 = X4[(size_t)(e0 & 0xFFFFu) * 16 + q];
        float w0 = bf_hi(e0);
        a0 += bf_lo(v0.x) * w0; a1 += bf_hi(v0.x) * w0; a2 += bf_lo(v0.y) * w0; a3 += bf_hi(v0.y) * w0;
        a4 += bf_lo(v0.z) * w0; a5 += bf_hi(v0.z) * w0; a6 += bf_lo(v0.w) * w0; a7 += bf_hi(v0.w) * w0;
    }
    ((u32x4*)aggbf)[(size_t)node * 16 + q] =
        (u32x4){pack_bf16(a0, a1), pack_bf16(a2, a3), pack_bf16(a4, a5), pack_bf16(a6, a7)};
}

// 32-dim bf16 z: 16 lanes per node, lane owns uint (2 features); unroll-4
__global__ __launch_bounds__(256) void agg32_kernel(
    const unsigned int* __restrict__ zbf, const int* __restrict__ cnt,
    const unsigned int* __restrict__ ep, unsigned int* __restrict__ aggbf, int n) {
    int tid = threadIdx.x;
    int wid = tid >> 6, l = tid & 63;
    int sub = l >> 4, q = l & 15;
    int node = blockIdx.x * 16 + wid * 4 + sub;
    if (node >= n) return;
    int deg = cnt[node]; if (deg > CAP) deg = CAP;
    const unsigned int* row = ep + (size_t)node * CAP;
    float a0 = 0.f, a1 = 0.f;
    int j = 0;
    for (; j + 4 <= deg; j += 4) {
        unsigned int e0 = __builtin_nontemporal_load(row + j);
        unsigned int e1 = __builtin_nontemporal_load(row + j + 1);
        unsigned int e2 = __builtin_nontemporal_load(row + j + 2);
        unsigned int e3 = __builtin_nontemporal_load(row + j + 3);
        unsigned int v0 = zbf[(size_t)(e0 & 0xFFFFu) * 16 + q];
        unsigned int v1 = zbf[(size_t)(e1 & 0xFFFFu) * 16 + q];
        unsigned int v2 = zbf[(size_t)(e2 & 0xFFFFu) * 16 + q];
        unsigned int v3 = zbf[(size_t)(e3 & 0xFFFFu) * 16 + q];
        float w0 = bf_hi(e0), w1 = bf_hi(e1), w2 = bf_hi(e2), w3 = bf_hi(e3);
        a0 += bf_lo(v0) * w0; a1 += bf_hi(v0) * w0;
        a0 += bf_lo(v1) * w1; a1 += bf_hi(v1) * w1;
        a0 += bf_lo(v2) * w2; a1 += bf_hi(v2) * w2;
        a0 += bf_lo(v3) * w3; a1 += bf_hi(v3) * w3;
    }
    for (; j < deg; j++) {
        unsigned int e0 = __builtin_nontemporal_load(row + j);
        unsigned int v0 = zbf[(size_t)(e0 & 0xFFFFu) * 16 + q];
        float w0 = bf_hi(e0);
        a0 += bf_lo(v0) * w0; a1 += bf_hi(v0) * w0;
    }
    aggbf[(size_t)node * 16 + q] = pack_bf16(a0, a1);
}

// ---------------- fused linear via MFMA (bf16 in, bf16/f32 out, row-major) ----------------
// out[n][128] = relu( [agg|x][n][2K] @ W2[128][2K]^T + b ) (+skip relu)
// LDS slot d (uint2) holds A elems k=ks*32+hi16*8+jh*4.. of row mt*16+r15,
// d = ((mt*NKS+ks)*64 + hi16*16 + r15)*2 + jh. GEMM reads Afr[(mt*NKS+ks)*64+l].

template <int KH, bool SKIP, bool FINAL>
__global__ __launch_bounds__(256) void lin_kernel(
    const unsigned short* __restrict__ agg, const unsigned short* __restrict__ x,
    const unsigned short* __restrict__ W2, const float* __restrict__ bias,
    void* __restrict__ outv, int n) {
    constexpr int K2 = 2 * KH;
    constexpr int NKS = K2 / 32;
    constexpr int LOGNKS = (NKS == 2) ? 1 : 3;
    constexpr int SLOTS = 16 * K2;
    __shared__ uint2 Abuf[SLOTS];
    const int tid = threadIdx.x;
    const int n0 = blockIdx.x * 64;

#pragma unroll
    for (int it = 0; it < SLOTS / 256; it++) {
        int d = tid + it * 256;
        int jh = d & 1;
        int l = (d >> 1) & 63;
        int ks = (d >> 7) & (NKS - 1);
        int mt = d >> (7 + LOGNKS);
        int r = mt * 16 + (l & 15);
        int k = ks * 32 + ((l >> 4) << 3) + jh * 4;
        int node = n0 + r;
        uint2 v = make_uint2(0u, 0u);
        if (node < n) {
            v = (k < KH) ? *(const uint2*)(agg + (size_t)node * KH + k)
                         : *(const uint2*)(x + (size_t)node * KH + (k - KH));
        }
        Abuf[d] = v;
    }
    __syncthreads();

    const int w = tid >> 6, l = tid & 63;
    const int lo16 = l & 15, hi = l >> 4;

    f32x4 acc[4][2];
#pragma unroll
    for (int nt = 0; nt < 2; nt++) {
        float bv = bias[w * 32 + nt * 16 + lo16];
#pragma unroll
        for (int mt = 0; mt < 4; mt++) acc[mt][nt] = (f32x4){bv, bv, bv, bv};
    }

    const short8* Afr = (const short8*)Abuf;
#pragma unroll
    for (int ks = 0; ks < NKS; ks++) {
        short8 bfr[2];
#pragma unroll
        for (int nt = 0; nt < 2; nt++) {
            int o = w * 32 + nt * 16 + lo16;
            bfr[nt] = *(const short8*)(W2 + (size_t)o * K2 + ks * 32 + hi * 8);
        }
#pragma unroll
        for (int mt = 0; mt < 4; mt++) {
            short8 afr = Afr[(mt * NKS + ks) * 64 + l];
            acc[mt][0] = __builtin_amdgcn_mfma_f32_16x16x32_bf16(afr, bfr[0], acc[mt][0], 0, 0, 0);
            acc[mt][1] = __builtin_amdgcn_mfma_f32_16x16x32_bf16(afr, bfr[1], acc[mt][1], 0, 0, 0);
        }
    }

    const unsigned short* Au16 = (const unsigned short*)Abuf;
#pragma unroll
    for (int mt = 0; mt < 4; mt++) {
#pragma unroll
        for (int j = 0; j < 4; j++) {
            int node = n0 + mt * 16 + hi * 4 + j;
            if (node < n) {
#pragma unroll
                for (int nt = 0; nt < 2; nt++) {
                    int o = w * 32 + nt * 16 + lo16;
                    float v = acc[mt][nt][j];
                    v = fmaxf(v, 0.f);
                    if (SKIP) {
                        // x[node][o] from staged LDS root half (k=128+o), bf16 — same value
                        int us = (((mt * NKS + 4 + w) * 64 + (nt * 2 + (lo16 >> 3)) * 16 + hi * 4 + j) * 2
                                  + ((lo16 >> 2) & 1)) * 4 + (lo16 & 3);
                        float xr = __uint_as_float((unsigned int)Au16[us] << 16);
                        v = fmaxf(v + xr, 0.f);
                    }
                    if (FINAL)
                        ((float*)outv)[(size_t)node * D_H + o] = v;
                    else
                        ((unsigned short*)outv)[(size_t)node * D_H + o] = f2bf(v);
                }
            }
        }
    }
}

// ---------------- launch ----------------

extern "C" void kernel_launch(void* const* d_in, const int* in_sizes, int n_in,
                              void* d_out, int out_size, void* d_ws, size_t ws_size,
                              hipStream_t stream) {
    const float* z      = (const float*)d_in[0];
    const int*   eidx   = (const int*)d_in[1];
    const float* ew     = (const float*)d_in[2];
    const float* Wrel0  = (const float*)d_in[4];
    const float* brel0  = (const float*)d_in[5];
    const float* Wroot0 = (const float*)d_in[6];
    const float* Wrel   = (const float*)d_in[7];
    const float* brel   = (const float*)d_in[8];
    const float* Wroot  = (const float*)d_in[9];

    const int* src = eidx;
    const int* dst = eidx + N_EDGES;

    char* p = (char*)d_ws;
    auto alloc = [&](size_t bytes) {
        void* r = (void*)p;
        p += (bytes + 255) & ~(size_t)255;
        return r;
    };
    int*   cnt    = (int*)alloc((size_t)N_NODES * 4);
    unsigned int* epack = (unsigned int*)alloc((size_t)N_NODES * CAP * 4);
    unsigned int* zbf = (unsigned int*)alloc((size_t)N_NODES * D_IN * 2);
    unsigned int* agg = (unsigned int*)alloc((size_t)N_NODES * D_H * 2);
    unsigned int* h0  = (unsigned int*)alloc((size_t)N_NODES * D_H * 2);
    unsigned int* h1  = (unsigned int*)alloc((size_t)N_NODES * D_H * 2);
    unsigned short* W0bf = (unsigned short*)alloc((size_t)128 * 64 * 2);
    unsigned short* W1bf = (unsigned short*)alloc((size_t)3 * 128 * 256 * 2);
    float* outp = (float*)d_out;

    // grid MUST cover the zbf clause: N_NODES*D_IN/4 = 400000 threads
    prep_kernel<<<cdiv(N_NODES * D_IN / 4, 256), 256, 0, stream>>>(
        z, zbf, Wrel0, Wroot0, Wrel, Wroot, W0bf, W1bf, cnt);

    // padded edge table (cnt -> degrees)
    fillpad_kernel<<<cdiv(N_EDGES, 256), 256, 0, stream>>>(src, dst, ew, cnt, epack, N_EDGES);

    const int aggGrid = cdiv(N_NODES, 16);
    const int linGrid = cdiv(N_NODES, 64);

    // L0: 32 -> 128 (no skip)
    agg32_kernel<<<aggGrid, 256, 0, stream>>>(zbf, cnt, epack, agg, N_NODES);
    lin_kernel<32, false, false><<<linGrid, 256, 0, stream>>>(
        (const unsigned short*)agg, (const unsigned short*)zbf, W0bf, brel0, h0, N_NODES);
    // L1 (skip)
    agg128_kernel<<<aggGrid, 256, 0, stream>>>(h0, cnt, epack, agg, N_NODES);
    lin_kernel<128, true, false><<<linGrid, 256, 0, stream>>>(
        (const unsigned short*)agg, (const unsigned short*)h0, W1bf, brel, h1, N_NODES);
    // L2 (skip)
    agg128_kernel<<<aggGrid, 256, 0, stream>>>(h1, cnt, epack, agg, N_NODES);
    lin_kernel<128, true, false><<<linGrid, 256, 0, stream>>>(
        (const unsigned short*)agg, (const unsigned short*)h1, W1bf + 32768, brel + 128, h0, N_NODES);
    // L3 (no skip) -> d_out (f32)
    agg128_kernel<<<aggGrid, 256, 0, stream>>>(h0, cnt, epack, agg, N_NODES);
    lin_kernel<128, false, true><<<linGrid, 256, 0, stream>>>(
        (const unsigned short*)agg, (const unsigned short*)h0, W1bf + 65536, brel + 256, outp, N_NODES);
}